// Round 6
// baseline (24677.501 us; speedup 1.0000x reference)
//
#include <hip/hip_runtime.h>

#define NP   19
#define EPB  16
#define BLK  256
#define RSTRIDE 4864

namespace {
constexpr int P_IO[NP]  = {0,0,0, 1,1,1,1,1,1,1, 2,2,2,2, 2,2,2,2,2};
constexpr int P_II[NP]  = {0,1,2, 0,1,1,1,2,2,2, 0,1,1,1, 2,2,2,2,2};
constexpr int P_LF[NP]  = {0,1,2, 1,0,1,2,1,2,3, 2,1,2,3, 0,1,2,3,4};
constexpr int P_CGB[NP+1] = {0,1,10, 35,44,53,80,125,170,245, 350,375,420,495, 600,625,700,825,1000, 1225};
constexpr float NORMLF[5] = {1.0f, 0.57735026918962576f, 0.44721359549995794f,
                             0.37796447300922722f, 0.33333333333333333f};

constexpr int ymin_of(int pb, int pe) {
    int m = 1000;
    for (int p = pb; p < pe; ++p) { int v = P_LF[p]*P_LF[p]; if (v < m) m = v; }
    return m;
}
constexpr int ymax_of(int pb, int pe) {
    int M = 0;
    for (int p = pb; p < pe; ++p) { int v = (P_LF[p]+1)*(P_LF[p]+1); if (v > M) M = v; }
    return M;
}
constexpr bool has_ii(int pb, int pe, int ii) {
    for (int p = pb; p < pe; ++p) if (P_II[p] == ii) return true;
    return false;
}
}

// ---------------- per-path body ----------------
template<int P, int PBEG, int PEND, int NY, int YLO, int TMPW>
__device__ __forceinline__ void do_paths(
    const int l, const int eloc,
    const float fA, const float (&fB)[3], const float (&fC)[5],
    const float (&rad)[10], const float (&y)[NY], float* __restrict__ acc,
    const float* __restrict__ s_R, const float* __restrict__ s_cg,
    float (*__restrict__ s_cgy)[25], float* __restrict__ s_tmp)
{
    if constexpr (P < PEND) {
        constexpr int io = P_IO[P], ii = P_II[P], lf = P_LF[P];
        constexpr int dO = 2*io+1, dI = 2*ii+1, dF = 2*lf+1;
        constexpr int nOI = dO*dI, yb = lf*lf;
        constexpr float nrm = NORMLF[lf];
        constexpr int cgo = P_CGB[P] - P_CGB[PBEG];
        constexpr int pl  = P - PBEG;

        // stage 1: cgY[o,i] = norm * sum_f cg[o,i,f] * Y[f]   (16 lanes cover (o,i))
#pragma unroll
        for (int j0 = 0; j0 < nOI; j0 += 16) {
            const int j = j0 + l;
            if (j < nOI) {
                float s = 0.f;
#pragma unroll
                for (int f = 0; f < dF; ++f)
                    s += s_cg[cgo + j*dF + f] * y[yb - YLO + f];
                s_cgy[eloc][j] = s * nrm;
            }
        }
        __syncthreads();

        // stage 2: tmp[v,o] = sum_i F[v,i] * cgY[o,i]   (lane = v)
#pragma unroll
        for (int o = 0; o < dO; ++o) {
            float t = 0.f;
#pragma unroll
            for (int i = 0; i < dI; ++i) {
                float fv;
                if constexpr (ii == 0)      fv = fA;
                else if constexpr (ii == 1) fv = fB[i];
                else                        fv = fC[i];
                t += fv * s_cgy[eloc][o*dI + i];
            }
            s_tmp[eloc*TMPW + o*16 + l] = t;
        }
        __syncthreads();

        // stage 3: per-lane W row from LDS-R (k-major layout), apply immediately.
        // W[v=4k+j] = sum_r rad[r] * R[r, P*256 + 16l + 4k + j]
        float4 W4[4];
#pragma unroll
        for (int k = 0; k < 4; ++k) { W4[k].x = 0.f; W4[k].y = 0.f; W4[k].z = 0.f; W4[k].w = 0.f; }
#pragma unroll
        for (int r = 0; r < 10; ++r) {
            const float rv = rad[r];
#pragma unroll
            for (int k = 0; k < 4; ++k) {
                const float4 q = *reinterpret_cast<const float4*>(
                    &s_R[((pl*10 + r)*4 + k)*64 + 4*l]);
                W4[k].x += rv*q.x; W4[k].y += rv*q.y; W4[k].z += rv*q.z; W4[k].w += rv*q.w;
            }
        }
#pragma unroll
        for (int o = 0; o < dO; ++o) {
            float s = 0.f;
#pragma unroll
            for (int k = 0; k < 4; ++k) {
                const float4 t = *reinterpret_cast<const float4*>(
                    &s_tmp[eloc*TMPW + o*16 + 4*k]);
                s += W4[k].x*t.x + W4[k].y*t.y + W4[k].z*t.z + W4[k].w*t.w;
            }
            acc[o] += s;
        }

        do_paths<P+1, PBEG, PEND, NY, YLO, TMPW>(l, eloc, fA, fB, fC, rad, y, acc,
                                                 s_R, s_cg, s_cgy, s_tmp);
    }
}

// ---------------- group kernel: paths [PBEG,PEND), node-major, persistent ----------------
template<int PBEG, int PEND, int OUTOFF, bool ACCUM, int WPE>
__global__ __launch_bounds__(BLK, WPE)
void se3_group(const float* __restrict__ F, const float* __restrict__ R,
               const float* __restrict__ Ys, const float* __restrict__ Rad,
               const float* __restrict__ cg, const float* __restrict__ Nn,
               const int* __restrict__ Mb,
               const int* __restrict__ off, const int* __restrict__ eidx,
               float* __restrict__ Out, const int nN)
{
    constexpr int NPL  = PEND - PBEG;
    constexpr int io   = P_IO[PBEG];
    constexpr int dO   = 2*io + 1;
    constexpr int TMPW = dO*16 + 4;
    constexpr int CGSZ = P_CGB[PEND] - P_CGB[PBEG];
    constexpr int YLO  = ymin_of(PBEG, PEND);
    constexpr int YHI  = ymax_of(PBEG, PEND);
    constexpr int NY   = YHI - YLO;
    constexpr bool H0  = has_ii(PBEG, PEND, 0);
    constexpr bool H1  = has_ii(PBEG, PEND, 1);
    constexpr bool H2  = has_ii(PBEG, PEND, 2);

    __shared__ float s_R[NPL * 2560];     // k-major permuted R slice
    __shared__ float s_cg[CGSZ];
    __shared__ float s_cgy[EPB][25];
    __shared__ float s_tmp[EPB * TMPW];   // epilogue aliases this as s_x

    const int tid  = threadIdx.x;
    const int l    = tid & 15;
    const int eloc = tid >> 4;

    // stage R slice into LDS (permuted: col c=16l+4k+j -> k*64 + 4l + j), once per block
    for (int t = tid; t < NPL * 2560; t += BLK) {
        const int p = t / 2560, rem = t - p*2560;
        const int r = rem >> 8, c = rem & 255;
        const int L = (p*10 + r)*256 + ((c>>2)&3)*64 + ((c>>4)<<2) + (c&3);
        s_R[L] = R[r*RSTRIDE + (PBEG + p)*256 + c];
    }
    for (int t = tid; t < CGSZ; t += BLK) s_cg[t] = cg[P_CGB[PBEG] + t];
    // visibility guaranteed by the chunk-head __syncthreads before first use

    for (int n = blockIdx.x; n < nN; n += gridDim.x) {
        const int ro0 = off[n];
        const int ro1 = off[n + 1];
        const int nCh = (ro1 - ro0 + EPB - 1) / EPB;

        float acc[dO];
#pragma unroll
        for (int o = 0; o < dO; ++o) acc[o] = 0.f;

        for (int c = 0; c < nCh; ++c) {
            const int  idx = ro0 + c*EPB + eloc;
            const bool act = (idx < ro1);
            const int  eid = act ? eidx[idx] : 0;
            const int  b   = Mb[eid];

            float rad[10];
            const float* rp = Rad + (size_t)eid * 10;
#pragma unroll
            for (int r = 0; r < 10; ++r) rad[r] = act ? rp[r] : 0.f;  // inactive -> W=0

            float y[NY];
            const float* yr = Ys + (size_t)eid * 25;
#pragma unroll
            for (int k = 0; k < NY; ++k) y[k] = yr[YLO + k];

            float fA = 0.f, fB[3] = {0.f,0.f,0.f}, fC[5] = {0.f,0.f,0.f,0.f,0.f};
            const float* Fb = F + (size_t)b * 144;
            if constexpr (H0) fA = Fb[l];
            if constexpr (H1) {
#pragma unroll
                for (int i = 0; i < 3; ++i) fB[i] = Fb[16 + l*3 + i];
            }
            if constexpr (H2) {
#pragma unroll
                for (int i = 0; i < 5; ++i) fC[i] = Fb[64 + l*5 + i];
            }

            __syncthreads();   // chunk head: staging visible (1st iter) / prior reads done

            do_paths<PBEG, PBEG, PEND, NY, YLO, TMPW>(l, eloc, fA, fB, fC, rad, y, acc,
                                                      s_R, s_cg, s_cgy, s_tmp);
        }

        // epilogue: cross-slot reduce via LDS (aliases s_tmp), plain store of our slice
        __syncthreads();                      // last stage-3 s_tmp reads done
        float* s_x = s_tmp;                   // s_x[slot][dO*16], dO*16 <= TMPW*... fits
#pragma unroll
        for (int o = 0; o < dO; ++o) s_x[eloc*(dO*16) + o*16 + l] = acc[o];
        __syncthreads();
        for (int t = tid; t < 16*dO; t += BLK) {
            const int ll = t / dO, oo = t - ll*dO;
            float s = 0.f;
#pragma unroll
            for (int sl = 0; sl < EPB; ++sl) s += s_x[sl*(dO*16) + oo*16 + ll];
            s *= Nn[n];
            float* po = Out + (size_t)n*144 + OUTOFF + t;   // [w,o] -> w*dO+o = t
            if constexpr (ACCUM) *po += s; else *po = s;
        }
        // next node's chunk-head barrier separates these reads from new writes
    }
}

// ---------------- CSR build (by destination) ----------------
__global__ void k_count(const int* __restrict__ Ma, int* __restrict__ cur, int E) {
    int e = blockIdx.x * blockDim.x + threadIdx.x;
    if (e < E) atomicAdd(&cur[Ma[e]], 1);
}

__global__ void k_scan(int* __restrict__ cur, int* __restrict__ off, int N) {
    __shared__ int part[BLK];
    const int t = threadIdx.x;
    const int K = (N + BLK - 1) / BLK;
    const int i0 = t * K, i1 = min(i0 + K, N);
    int s = 0;
    for (int i = i0; i < i1; ++i) s += cur[i];
    part[t] = s;
    __syncthreads();
    if (t == 0) {
        int a = 0;
        for (int j = 0; j < BLK; ++j) { int v = part[j]; part[j] = a; a += v; }
        off[N] = a;
    }
    __syncthreads();
    int a = part[t];
    for (int i = i0; i < i1; ++i) {
        int v = cur[i];
        off[i] = a;
        cur[i] = a;       // reset as scatter cursor
        a += v;
    }
}

__global__ void k_scatter(const int* __restrict__ Ma, int* __restrict__ cur,
                          int* __restrict__ eidx, int E) {
    int e = blockIdx.x * blockDim.x + threadIdx.x;
    if (e < E) {
        int pos = atomicAdd(&cur[Ma[e]], 1);
        eidx[pos] = e;
    }
}

extern "C" void kernel_launch(void* const* d_in, const int* in_sizes, int n_in,
                              void* d_out, int out_size, void* d_ws, size_t ws_size,
                              hipStream_t stream) {
    const float* F   = (const float*)d_in[0];
    const float* R   = (const float*)d_in[1];
    const float* Ys  = (const float*)d_in[2];
    const float* Rad = (const float*)d_in[3];
    const float* cg  = (const float*)d_in[4];
    const float* Nn  = (const float*)d_in[5];
    const int*   Ma  = (const int*)d_in[6];
    const int*   Mb  = (const int*)d_in[7];
    float* Out = (float*)d_out;

    const int nE = in_sizes[6];   // edges
    const int nN = in_sizes[5];   // nodes

    int* wsI  = (int*)d_ws;
    int* cur  = wsI;              // [nN]
    int* off  = wsI + nN;         // [nN+1]
    int* eidx = wsI + 2*nN + 1;   // [nE]

    hipMemsetAsync(cur, 0, (size_t)nN * sizeof(int), stream);
    k_count  <<<(nE + BLK - 1) / BLK, BLK, 0, stream>>>(Ma, cur, nE);
    k_scan   <<<1, BLK, 0, stream>>>(cur, off, nN);
    k_scatter<<<(nE + BLK - 1) / BLK, BLK, 0, stream>>>(Ma, cur, eidx, nE);

    // G0: io=0, paths 0-2   (LDS ~34 KB, 4 blk/CU)  -> Out[:, 0:16)
    se3_group<0, 3, 0, false, 4><<<1024, BLK, 0, stream>>>(F, R, Ys, Rad, cg, Nn, Mb, off, eidx, Out, nN);
    // G1: io=1, paths 3-9   (LDS ~78 KB, 2 blk/CU)  -> Out[:, 16:64)
    se3_group<3, 10, 16, false, 2><<<512, BLK, 0, stream>>>(F, R, Ys, Rad, cg, Nn, Mb, off, eidx, Out, nN);
    // G2a: io=2, paths 10-13 (LDS ~49 KB, 3 blk/CU) -> Out[:, 64:144) store
    se3_group<10, 14, 64, false, 3><<<768, BLK, 0, stream>>>(F, R, Ys, Rad, cg, Nn, Mb, off, eidx, Out, nN);
    // G2b: io=2, paths 14-18 (LDS ~61 KB, 2 blk/CU) -> Out[:, 64:144) accumulate
    se3_group<14, 19, 64, true, 2><<<512, BLK, 0, stream>>>(F, R, Ys, Rad, cg, Nn, Mb, off, eidx, Out, nN);
}

// Round 7
// 8721.141 us; speedup vs baseline: 2.8296x; 2.8296x over previous
//
#include <hip/hip_runtime.h>

#define NP   19
#define EPB  16
#define BLK  256
#define WST  260        // s_W row stride (words): mult of 4 + pad
#define RSTRIDE 4864    // P_TOTAL columns in R

namespace {
constexpr int P_IO[NP]  = {0,0,0, 1,1,1,1,1,1,1, 2,2,2,2, 2,2,2,2,2};
constexpr int P_II[NP]  = {0,1,2, 0,1,1,1,2,2,2, 0,1,1,1, 2,2,2,2,2};
constexpr int P_LF[NP]  = {0,1,2, 1,0,1,2,1,2,3, 2,1,2,3, 0,1,2,3,4};
constexpr int P_CGB[NP] = {0,1,10, 35,44,53,80,125,170,245, 350,375,420,495, 600,625,700,825,1000};
constexpr float NORMLF[5] = {1.0f, 0.57735026918962576f, 0.44721359549995794f,
                             0.37796447300922722f, 0.33333333333333333f};
}

// ---------------- Phase A per-path body ----------------
// Single barrier per path: s_W and s_tmp double-buffered by path parity.
template<int P>
__device__ __forceinline__ void process_path(
    const int tid, const int l, const int eloc,
    const float fA, const float (&fB)[3], const float (&fC)[5],
    const float (&y)[25], float (&acc)[9],
    const float* __restrict__ R, const float* __restrict__ s_cg,
    const float (*__restrict__ s_rad)[10],
    float* __restrict__ s_W, float* __restrict__ s_tmp)
{
    constexpr int io = P_IO[P], ii = P_II[P], lf = P_LF[P];
    constexpr int dO = 2*io+1, dI = 2*ii+1, dF = 2*lf+1;
    constexpr int nOI = dO*dI, yb = lf*lf;
    constexpr float nrm = NORMLF[lf];
    constexpr int wOff = (P & 1) * (EPB * WST);
    constexpr int tOff = (P & 1) * (EPB * 84);

    // --- W coop: thread owns column c=tid; R loads coalesced, s_rad broadcast ---
    {
        float rcol[10];
        const float* Rp = R + P*256 + tid;
#pragma unroll
        for (int r = 0; r < 10; ++r) rcol[r] = Rp[r * RSTRIDE];
#pragma unroll
        for (int e = 0; e < EPB; ++e) {
            float s = 0.f;
#pragma unroll
            for (int r = 0; r < 10; ++r) s += s_rad[e][r] * rcol[r];
            s_W[wOff + e*WST + tid] = s;
        }
    }

    // --- cgY in registers, computed redundantly by every lane (broadcast s_cg reads,
    //     private y). Removes the cgY LDS exchange + its barrier. ---
    float cgy[nOI];
#pragma unroll
    for (int j = 0; j < nOI; ++j) {
        float s = 0.f;
#pragma unroll
        for (int f = 0; f < dF; ++f)
            s += s_cg[P_CGB[P] + j*dF + f] * y[yb + f];
        cgy[j] = s * nrm;
    }

    // --- tmp[v,o] = sum_i F[v,i] * cgY[o,i]   (lane = v) ---
#pragma unroll
    for (int o = 0; o < dO; ++o) {
        float t = 0.f;
#pragma unroll
        for (int i = 0; i < dI; ++i) {
            float fv;
            if constexpr (ii == 0)      fv = fA;
            else if constexpr (ii == 1) fv = fB[i];
            else                        fv = fC[i];
            t += fv * cgy[o*dI + i];
        }
        s_tmp[tOff + eloc*84 + o*16 + l] = t;
    }

    __syncthreads();   // the ONE barrier: W+tmp of this path visible; prior-path
                       // reads (other buffer) were sequenced by the previous barrier

    // --- out[w,o] += sum_v W[w,v] * tmp[v,o]   (lane = w) ---
    const float* Wrow = &s_W[wOff + eloc*WST + 16*l];
    const float4 w0 = *reinterpret_cast<const float4*>(Wrow);
    const float4 w1 = *reinterpret_cast<const float4*>(Wrow + 4);
    const float4 w2 = *reinterpret_cast<const float4*>(Wrow + 8);
    const float4 w3 = *reinterpret_cast<const float4*>(Wrow + 12);
#pragma unroll
    for (int o = 0; o < dO; ++o) {
        const float4* tq = reinterpret_cast<const float4*>(&s_tmp[tOff + eloc*84 + o*16]);
        const float4 t0 = tq[0], t1 = tq[1], t2 = tq[2], t3 = tq[3];
        float s = w0.x*t0.x + w0.y*t0.y + w0.z*t0.z + w0.w*t0.w
                + w1.x*t1.x + w1.y*t1.y + w1.z*t1.z + w1.w*t1.w
                + w2.x*t2.x + w2.y*t2.y + w2.z*t2.z + w2.w*t2.w
                + w3.x*t3.x + w3.y*t3.y + w3.z*t3.z + w3.w*t3.w;
        acc[io*io + o] += s;
    }
}

template<int P>
__device__ __forceinline__ void process_all(
    const int tid, const int l, const int eloc,
    const float fA, const float (&fB)[3], const float (&fC)[5],
    const float (&y)[25], float (&acc)[9],
    const float* __restrict__ R, const float* __restrict__ s_cg,
    const float (*__restrict__ s_rad)[10],
    float* __restrict__ s_W, float* __restrict__ s_tmp)
{
    if constexpr (P < NP) {
        process_path<P>(tid, l, eloc, fA, fB, fC, y, acc, R, s_cg, s_rad, s_W, s_tmp);
        process_all<P+1>(tid, l, eloc, fA, fB, fC, y, acc, R, s_cg, s_rad, s_W, s_tmp);
    }
}

// ---------------- Phase A: edge-major message materialization ----------------
__global__ __launch_bounds__(BLK, 3)
void se3_msg(const float* __restrict__ F, const float* __restrict__ R,
             const float* __restrict__ Ys, const float* __restrict__ Rad,
             const float* __restrict__ cg,
             const int* __restrict__ Mb,
             float* __restrict__ msg, const int nE)
{
    __shared__ float s_cg[1225];
    __shared__ float s_rad[EPB][10];
    __shared__ float s_W[2 * EPB * WST];
    __shared__ float s_tmp[2 * EPB * 84];

    const int tid  = threadIdx.x;
    const int l    = tid & 15;
    const int eloc = tid >> 4;
    const int e    = blockIdx.x * EPB + eloc;
    const bool act = (e < nE);
    const int  es  = act ? e : 0;

    for (int j = tid; j < 1225; j += BLK) s_cg[j] = cg[j];
    if (tid < EPB * 10) {
        const int se = tid / 10, sr = tid - se * 10;
        const int ge = blockIdx.x * EPB + se;
        s_rad[se][sr] = (ge < nE) ? Rad[ge * 10 + sr] : 0.f;   // inactive -> W = 0
    }

    const int b = Mb[es];
    const float* Fb = F + (size_t)b * 144;
    const float fA = Fb[l];
    float fB[3], fC[5];
#pragma unroll
    for (int i = 0; i < 3; ++i) fB[i] = Fb[16 + l*3 + i];
#pragma unroll
    for (int i = 0; i < 5; ++i) fC[i] = Fb[64 + l*5 + i];

    float y[25];
    const float* yr = Ys + (size_t)es * 25;
#pragma unroll
    for (int k = 0; k < 25; ++k) y[k] = yr[k];

    float acc[9];
#pragma unroll
    for (int k = 0; k < 9; ++k) acc[k] = 0.f;

    __syncthreads();   // s_cg + s_rad staged

    process_all<0>(tid, l, eloc, fA, fB, fC, y, acc, R, s_cg, s_rad, s_W, s_tmp);

    // tail: plain coalesced stores, transposed [j][16] layout — no LDS, no atomics
    if (act) {
        float* m = msg + (size_t)e * 144 + l;
#pragma unroll
        for (int j = 0; j < 9; ++j) m[j * 16] = acc[j];
    }
}

// ---------------- Phase B: node gather-reduce (no atomics) ----------------
__global__ __launch_bounds__(BLK)
void se3_gather(const float* __restrict__ msg, const int* __restrict__ off,
                const int* __restrict__ eidx, const float* __restrict__ Nn,
                float* __restrict__ Out, const int nN)
{
    const int l = threadIdx.x & 15;
    const int g = threadIdx.x >> 4;
    const int n = blockIdx.x * 16 + g;
    if (n >= nN) return;

    const int i0 = off[n], i1 = off[n + 1];
    float s[9];
#pragma unroll
    for (int j = 0; j < 9; ++j) s[j] = 0.f;

    for (int idx = i0; idx < i1; ++idx) {
        const int eid = eidx[idx];                 // uniform across the 16-lane group
        const float* m = msg + (size_t)eid * 144 + l;
#pragma unroll
        for (int j = 0; j < 9; ++j) s[j] += m[j * 16];   // 9 independent 64B-coalesced loads
    }

    const float nn = Nn[n];
    float* orow = Out + (size_t)n * 144;
    orow[l] = s[0] * nn;
#pragma unroll
    for (int o = 0; o < 3; ++o) orow[16 + l*3 + o] = s[1+o] * nn;
#pragma unroll
    for (int o = 0; o < 5; ++o) orow[64 + l*5 + o] = s[4+o] * nn;
}

// ---------------- CSR build (by destination) ----------------
__global__ void k_count(const int* __restrict__ Ma, int* __restrict__ cur, int E) {
    int e = blockIdx.x * blockDim.x + threadIdx.x;
    if (e < E) atomicAdd(&cur[Ma[e]], 1);
}

__global__ void k_scan(int* __restrict__ cur, int* __restrict__ off, int N) {
    __shared__ int part[BLK];
    const int t = threadIdx.x;
    const int K = (N + BLK - 1) / BLK;
    const int i0 = t * K, i1 = min(i0 + K, N);
    int s = 0;
    for (int i = i0; i < i1; ++i) s += cur[i];
    part[t] = s;
    __syncthreads();
    if (t == 0) {
        int a = 0;
        for (int j = 0; j < BLK; ++j) { int v = part[j]; part[j] = a; a += v; }
        off[N] = a;
    }
    __syncthreads();
    int a = part[t];
    for (int i = i0; i < i1; ++i) {
        int v = cur[i];
        off[i] = a;
        cur[i] = a;       // reuse as scatter cursor
        a += v;
    }
}

__global__ void k_scatter(const int* __restrict__ Ma, int* __restrict__ cur,
                          int* __restrict__ eidx, int E) {
    int e = blockIdx.x * blockDim.x + threadIdx.x;
    if (e < E) {
        int pos = atomicAdd(&cur[Ma[e]], 1);
        eidx[pos] = e;
    }
}

extern "C" void kernel_launch(void* const* d_in, const int* in_sizes, int n_in,
                              void* d_out, int out_size, void* d_ws, size_t ws_size,
                              hipStream_t stream) {
    const float* F   = (const float*)d_in[0];
    const float* R   = (const float*)d_in[1];
    const float* Ys  = (const float*)d_in[2];
    const float* Rad = (const float*)d_in[3];
    const float* cg  = (const float*)d_in[4];
    const float* Nn  = (const float*)d_in[5];
    const int*   Ma  = (const int*)d_in[6];
    const int*   Mb  = (const int*)d_in[7];
    float* Out = (float*)d_out;

    const int nE = in_sizes[6];   // edges
    const int nN = in_sizes[5];   // nodes

    // ws layout: [cur nN][off nN+1][eidx nE][pad][msg nE*144 floats]
    int* wsI  = (int*)d_ws;
    int* cur  = wsI;
    int* off  = wsI + nN;
    int* eidx = wsI + 2*nN + 1;
    size_t msgOff = ((size_t)(2*nN + 1 + nE) + 63) & ~(size_t)63;
    float* msg = (float*)d_ws + msgOff;

    hipMemsetAsync(cur, 0, (size_t)nN * sizeof(int), stream);
    k_count  <<<(nE + BLK - 1) / BLK, BLK, 0, stream>>>(Ma, cur, nE);
    k_scan   <<<1, BLK, 0, stream>>>(cur, off, nN);
    k_scatter<<<(nE + BLK - 1) / BLK, BLK, 0, stream>>>(Ma, cur, eidx, nE);

    se3_msg   <<<(nE + EPB - 1) / EPB, BLK, 0, stream>>>(F, R, Ys, Rad, cg, Mb, msg, nE);
    se3_gather<<<(nN + 15) / 16, BLK, 0, stream>>>(msg, off, eidx, Nn, Out, nN);
}